// Round 1
// 612.253 us; speedup vs baseline: 1.0058x; 1.0058x over previous
//
#include <hip/hip_runtime.h>

// Shapes fixed by the problem: B=1, H=32, L=8192, S=16384, D=128, g=4.
// Reference reduces to: out_k[h,i,:] = k_val[h,keep[i],:] where
// keep[i] = i (i<4) else i + (S-L); same for V; pos[i] = 1e9 for i<4 else i+(S-L).
// Pure streaming gather-copy: 536.9 MB mandatory traffic -> ~85 us @ 6.3 TB/s.

#define HH 32
#define LL 8192
#define SS 16384
#define DD 128
#define GG 4
#define ROW4 (DD / 4)              // 32 float4 per row
#define PER_T (HH * LL * ROW4)     // 8,388,608 float4 per output tensor

// HIP's float4 is a struct; nontemporal builtins need a real vector type.
typedef float f32x4 __attribute__((ext_vector_type(4)));

__global__ __launch_bounds__(256) void fused_gather_pos(
    const f32x4* __restrict__ k_val, const f32x4* __restrict__ v_val,
    const int* __restrict__ input_pos,
    f32x4* __restrict__ out_k, f32x4* __restrict__ out_v,
    float* __restrict__ out_p)
{
    int tid = blockIdx.x * 256 + threadIdx.x;

    if (tid < 2 * PER_T) {
        // KV gather-copy. Block-uniform branch: PER_T is a multiple of 256.
        const bool is_v = tid >= PER_T;
        const f32x4* __restrict__ src = is_v ? v_val : k_val;
        f32x4* __restrict__ dst       = is_v ? out_v : out_k;

        int t = tid & (PER_T - 1);
        // t = ((h * LL) + i) * ROW4 + c ; LL*ROW4 = 2^18, ROW4 = 2^5
        int h = t >> 18;
        int i = (t >> 5) & (LL - 1);
        int c = t & (ROW4 - 1);

        int src_row = (i < GG) ? i : i + (SS - LL);
        // src offset = (h*SS + src_row)*ROW4 + c ; h*SS = h<<14
        int src_off = (((h << 14) + src_row) << 5) | c;

        // Streaming data (536 MB > 256 MB LLC): bypass cache allocation.
        f32x4 val = __builtin_nontemporal_load(src + src_off);
        __builtin_nontemporal_store(val, dst + t);
    } else {
        // pos tail: exactly LL threads (grid sized so tail == LL).
        int i = tid - 2 * PER_T;
        int keep_i = (i < GG) ? i : i + (SS - LL);
        int p = input_pos[keep_i];
        out_p[i] = (p >= 0 && p < GG) ? 1000000000.0f : (float)p;
    }
}

extern "C" void kernel_launch(void* const* d_in, const int* in_sizes, int n_in,
                              void* d_out, int out_size, void* d_ws, size_t ws_size,
                              hipStream_t stream) {
    // inputs: 0 k_cache, 1 v_cache, 2 k_val, 3 v_val, 4 pos, 5 input_pos
    const f32x4* k_val = (const f32x4*)d_in[2];
    const f32x4* v_val = (const f32x4*)d_in[3];
    const int* input_pos = (const int*)d_in[5];

    f32x4* out_k = (f32x4*)d_out;
    f32x4* out_v = out_k + PER_T;
    float* out_p = (float*)d_out + (size_t)2 * HH * LL * DD;

    // 2*PER_T copy threads + LL pos threads, all multiples of 256.
    int total = 2 * PER_T + LL;
    fused_gather_pos<<<total / 256, 256, 0, stream>>>(
        k_val, v_val, input_pos, out_k, out_v, out_p);
}